// Round 3
// baseline (341.232 us; speedup 1.0000x reference)
//
#include <hip/hip_runtime.h>
#include <math.h>
#include <stdint.h>

#define Bb 64
#define Ss 512
#define Tt 32
#define H2 1024   // feature dim of h
#define FF 2048   // w1_w row stride
#define ATT 512
#define MM (Bb * Ss)

#define BM 64
#define BN 512
#define BK 32

typedef short bf8 __attribute__((ext_vector_type(8)));   // 8 bf16 (4 VGPR) MFMA A/B frag
typedef short bf4 __attribute__((ext_vector_type(4)));   // 4 bf16 for ds_write_b64
typedef float f4 __attribute__((ext_vector_type(4)));

// fp32 -> bf16 (RNE), bit-level
__device__ __forceinline__ unsigned short f2bf(float f) {
    unsigned u = __float_as_uint(f);
    u = (u + 0x7fffu + ((u >> 16) & 1u)) >> 16;
    return (unsigned short)u;
}

__device__ __forceinline__ void gl_lds16(const void* g, void* l) {
    __builtin_amdgcn_global_load_lds((const __attribute__((address_space(1))) void*)g,
                                     (__attribute__((address_space(3))) void*)l, 16, 0, 0);
}

// ---------------------------------------------------------------- init (out only; wsum atomics need zeros)
__global__ void init_kernel(float* __restrict__ out) {
    int i = blockIdx.x * 256 + threadIdx.x;
    out[i] = 0.0f;
}

// ---------------------------------------------------------------- ht mean over T
__global__ void mean_kernel(const float* __restrict__ ht, float* __restrict__ ht_mean) {
    int b = blockIdx.x;
    int d4 = threadIdx.x;
    const float4* p = (const float4*)(ht + (size_t)b * Tt * H2);
    float4 acc = make_float4(0.f, 0.f, 0.f, 0.f);
    #pragma unroll 4
    for (int t = 0; t < Tt; ++t) {
        float4 v = p[(size_t)t * (H2 / 4) + d4];
        acc.x += v.x; acc.y += v.y; acc.z += v.z; acc.w += v.w;
    }
    const float inv = 1.0f / (float)Tt;
    acc.x *= inv; acc.y *= inv; acc.z *= inv; acc.w *= inv;
    ((float4*)(ht_mean + (size_t)b * H2))[d4] = acc;
}

// ---------------------------------------------------------------- c2[b,a] = ht_mean[b].w1_w[a,1024:] + w1_b[a]
__global__ __launch_bounds__(256) void c2_kernel2(const float* __restrict__ ht_mean,
                                                  const float* __restrict__ w1_w,
                                                  const float* __restrict__ w1_b,
                                                  float* __restrict__ c2) {
    __shared__ float hm[H2];
    int b = blockIdx.x;
    for (int i = threadIdx.x; i < H2; i += 256) hm[i] = ht_mean[(size_t)b * H2 + i];
    __syncthreads();
    int a = blockIdx.y * 64 + ((int)threadIdx.x >> 2);
    int q = (int)threadIdx.x & 3;
    const float4* w   = (const float4*)(w1_w + (size_t)a * FF + H2 + q * 256);
    const float4* hm4 = (const float4*)(hm + q * 256);
    float acc = 0.f;
    #pragma unroll 8
    for (int k = 0; k < 64; ++k) {
        float4 wv = w[k]; float4 hv = hm4[k];
        acc += wv.x * hv.x + wv.y * hv.y + wv.z * hv.z + wv.w * hv.w;
    }
    acc += __shfl_xor(acc, 1);
    acc += __shfl_xor(acc, 2);
    if (q == 0) c2[(size_t)b * ATT + a] = acc + w1_b[a];
}

// ---------------------------------------------------------------- w1a_bf[a][k] = bf16(w1_w[a][k]), k<1024
__global__ void convw_kernel(const float* __restrict__ w1_w, unsigned short* __restrict__ out) {
    size_t e = ((size_t)blockIdx.x * 256 + threadIdx.x) * 8;
    int row = (int)(e >> 10);
    int c = (int)(e & 1023);
    const float* src = w1_w + (size_t)row * FF + c;
    float4 a = *(const float4*)(src);
    float4 b = *(const float4*)(src + 4);
    bf8 v = { (short)f2bf(a.x), (short)f2bf(a.y), (short)f2bf(a.z), (short)f2bf(a.w),
              (short)f2bf(b.x), (short)f2bf(b.y), (short)f2bf(b.z), (short)f2bf(b.w) };
    *(bf8*)(out + e) = v;
}

// ---------------------------------------------------------------- fused GEMM: M=32768, N=512(full), K=1024
// BM=64 x BN=512 tile, BK=32, 8 waves (1m x 8n), wave tile 64x64. fp32 h converted in-reg.
// beta written exactly once per row (cross-wave LDS reduce) -> no atomics.
__global__ __launch_bounds__(512) void gemm_fused_kernel(
        const float* __restrict__ h, const unsigned short* __restrict__ wb,
        const float* __restrict__ c2, const float* __restrict__ u_w,
        float* __restrict__ beta) {
    __shared__ __align__(16) unsigned short As[BM][BK];    // 4 KB  [m][k]
    __shared__ __align__(16) unsigned short Bs[BN][BK];    // 32 KB [n][k]
    __shared__ float red[8][64];                           // 2 KB cross-wave beta partials

    const int tid = (int)threadIdx.x;
    const int m0 = blockIdx.x * BM;
    const int wid = tid >> 6, lane = tid & 63;
    const int col = lane & 15, rg = lane >> 4;

    f4 acc[4][4] = {};

    // A staging: thread -> (row, 4-float k-chunk), fp32 load + convert + ds_write_b64
    const int arow = tid >> 3;            // 0..63
    const int aq   = (tid & 7) * 4;       // k offset 0..28
    const float* Ag = h + (size_t)(m0 + arow) * H2 + aq;
    // B staging: 4 global_load_lds calls, call c covers rows c*128 + tid>>2
    const int brow = tid >> 2;            // 0..127
    const int bq   = (tid & 3) * 8;       // k offset in elements (16B chunk)
    unsigned short* lB = &Bs[0][0] + (size_t)wid * 512;    // + c*4096 elems; HW adds lane*16B

    for (int k0 = 0; k0 < H2; k0 += BK) {
        #pragma unroll
        for (int c = 0; c < 4; ++c)
            gl_lds16(wb + (size_t)(c * 128 + brow) * H2 + k0 + bq, lB + c * 4096);
        float4 a4 = *(const float4*)(Ag + k0);
        bf4 ab = { (short)f2bf(a4.x), (short)f2bf(a4.y), (short)f2bf(a4.z), (short)f2bf(a4.w) };
        *(bf4*)&As[arow][aq] = ab;
        __syncthreads();   // drains vmcnt (gl_lds) + lgkm (ds_write)
        bf8 av[4], bv[4];
        #pragma unroll
        for (int i = 0; i < 4; ++i) {
            av[i] = *(const bf8*)&As[i * 16 + col][rg * 8];
            bv[i] = *(const bf8*)&Bs[wid * 64 + i * 16 + col][rg * 8];
        }
        #pragma unroll
        for (int i = 0; i < 4; ++i)
            #pragma unroll
            for (int j = 0; j < 4; ++j)
                acc[i][j] = __builtin_amdgcn_mfma_f32_16x16x32_bf16(av[i], bv[j], acc[i][j], 0, 0, 0);
        __syncthreads();   // before next-tile overwrite
    }

    // epilogue: rp[i][r] = sum_n tanh(acc + c2[n]) * u[n] over this wave's 64-col strip
    const int b_idx = blockIdx.x >> 3;     // m0 / Ss
    const float* c2b = c2 + (size_t)b_idx * ATT + wid * 64;
    const float* ub  = u_w + wid * 64;
    float rp[4][4] = {};
    #pragma unroll
    for (int j = 0; j < 4; ++j) {
        int n = j * 16 + col;
        float cv = c2b[n];
        float uv = ub[n];
        #pragma unroll
        for (int i = 0; i < 4; ++i)
            #pragma unroll
            for (int r = 0; r < 4; ++r)
                rp[i][r] += tanhf(acc[i][j][r] + cv) * uv;
    }
    #pragma unroll
    for (int i = 0; i < 4; ++i)
        #pragma unroll
        for (int r = 0; r < 4; ++r) {
            float v = rp[i][r];
            v += __shfl_xor(v, 1);
            v += __shfl_xor(v, 2);
            v += __shfl_xor(v, 4);
            v += __shfl_xor(v, 8);
            if (col == 0) red[wid][i * 16 + rg * 4 + r] = v;
        }
    __syncthreads();
    if (tid < 64) {
        float s = 0.f;
        #pragma unroll
        for (int w = 0; w < 8; ++w) s += red[w][tid];
        beta[(size_t)m0 + tid] = s;
    }
}

// ---------------------------------------------------------------- masked softmax over S
__global__ void softmax_kernel(const float* __restrict__ beta, const int* __restrict__ h_mask,
                               float* __restrict__ alpha) {
    __shared__ float red[16];
    int b = blockIdx.x;
    int s = (int)threadIdx.x;
    float v = (h_mask[(size_t)b * Ss + s] != 0) ? beta[(size_t)b * Ss + s] : -1e20f;
    float m = v;
    #pragma unroll
    for (int off = 32; off >= 1; off >>= 1) m = fmaxf(m, __shfl_xor(m, off, 64));
    int wave = s >> 6;
    if ((s & 63) == 0) red[wave] = m;
    __syncthreads();
    float mx = red[0];
    #pragma unroll
    for (int w = 1; w < 8; ++w) mx = fmaxf(mx, red[w]);
    float e = expf(v - mx);
    float sum = e;
    #pragma unroll
    for (int off = 32; off >= 1; off >>= 1) sum += __shfl_xor(sum, off, 64);
    __syncthreads();
    if ((s & 63) == 0) red[8 + wave] = sum;
    __syncthreads();
    float tot = 0.f;
    #pragma unroll
    for (int w = 0; w < 8; ++w) tot += red[8 + w];
    alpha[(size_t)b * Ss + s] = e / tot;
}

// ---------------------------------------------------------------- s[b,d] = sum_s alpha[b,s] h[b,s,d]
__global__ void wsum_kernel(const float* __restrict__ h, const float* __restrict__ alpha,
                            float* __restrict__ out) {
    int b = blockIdx.x;
    int d = blockIdx.y * 256 + (int)threadIdx.x;
    int s0 = blockIdx.z * 128;
    const float* hp = h + (size_t)b * Ss * H2 + (size_t)s0 * H2 + d;
    const float* ap = alpha + (size_t)b * Ss + s0;
    float acc = 0.f;
    #pragma unroll 4
    for (int s = 0; s < 128; ++s) acc = fmaf(ap[s], hp[(size_t)s * H2], acc);
    atomicAdd(&out[(size_t)b * H2 + d], acc);
}

// ---------------------------------------------------------------- launch
extern "C" void kernel_launch(void* const* d_in, const int* in_sizes, int n_in,
                              void* d_out, int out_size, void* d_ws, size_t ws_size,
                              hipStream_t stream) {
    const float* h      = (const float*)d_in[0];
    const int*   h_mask = (const int*)d_in[1];
    const float* ht     = (const float*)d_in[2];
    const float* w1_w   = (const float*)d_in[3];
    const float* w1_b   = (const float*)d_in[4];
    const float* u_w    = (const float*)d_in[5];
    float* out = (float*)d_out;

    float* ws      = (float*)d_ws;
    float* ht_mean = ws;                 // 65536 floats
    float* c2      = ws + 65536;         // 32768
    float* beta    = ws + 98304;         // 32768
    float* alpha   = ws + 131072;        // 32768
    unsigned short* w1a_bf = (unsigned short*)(ws + 164864);   // 512K us = 1 MB  (total ~1.7 MB)

    hipLaunchKernelGGL(init_kernel, dim3(Bb * H2 / 256), dim3(256), 0, stream, out);
    hipLaunchKernelGGL(mean_kernel, dim3(Bb), dim3(256), 0, stream, ht, ht_mean);
    hipLaunchKernelGGL(c2_kernel2, dim3(Bb, 8), dim3(256), 0, stream, ht_mean, w1_w, w1_b, c2);
    hipLaunchKernelGGL(convw_kernel, dim3(256), dim3(256), 0, stream, w1_w, w1a_bf);
    hipLaunchKernelGGL(gemm_fused_kernel, dim3(MM / BM), dim3(512), 0, stream,
                       h, w1a_bf, c2, u_w, beta);
    hipLaunchKernelGGL(softmax_kernel, dim3(Bb), dim3(512), 0, stream, beta, h_mask, alpha);
    hipLaunchKernelGGL(wsum_kernel, dim3(Bb, H2 / 256, 4), dim3(256), 0, stream, h, alpha, out);
}

// Round 4
// 294.366 us; speedup vs baseline: 1.1592x; 1.1592x over previous
//
#include <hip/hip_runtime.h>
#include <math.h>
#include <stdint.h>

#define Bb 64
#define Ss 512
#define Tt 32
#define H2 1024   // feature dim of h
#define FF 2048   // w1_w row stride
#define ATT 512
#define MM (Bb * Ss)

#define BM 64
#define BN 512
#define BK 32

typedef short bf8 __attribute__((ext_vector_type(8)));   // 8 bf16 MFMA A/B frag
typedef short bf4 __attribute__((ext_vector_type(4)));   // 4 bf16 for ds_write_b64
typedef float f4 __attribute__((ext_vector_type(4)));

// fp32 -> bf16 (RNE), bit-level
__device__ __forceinline__ unsigned short f2bf(float f) {
    unsigned u = __float_as_uint(f);
    u = (u + 0x7fffu + ((u >> 16) & 1u)) >> 16;
    return (unsigned short)u;
}

__device__ __forceinline__ void gl_lds16(const void* g, void* l) {
    __builtin_amdgcn_global_load_lds((const __attribute__((address_space(1))) void*)g,
                                     (__attribute__((address_space(3))) void*)l, 16, 0, 0);
}

// fast tanh via v_exp_f32 path; saturates correctly at +-inf
__device__ __forceinline__ float tanh_fast(float x) {
    return 1.0f - 2.0f / (__expf(2.0f * x) + 1.0f);
}

// ---------------------------------------------------------------- init (out only; wsum atomics need zeros)
__global__ void init_kernel(float* __restrict__ out) {
    int i = blockIdx.x * 256 + threadIdx.x;
    out[i] = 0.0f;
}

// ---------------------------------------------------------------- ht mean over T
__global__ void mean_kernel(const float* __restrict__ ht, float* __restrict__ ht_mean) {
    int b = blockIdx.x;
    int d4 = threadIdx.x;
    const float4* p = (const float4*)(ht + (size_t)b * Tt * H2);
    float4 acc = make_float4(0.f, 0.f, 0.f, 0.f);
    #pragma unroll 4
    for (int t = 0; t < Tt; ++t) {
        float4 v = p[(size_t)t * (H2 / 4) + d4];
        acc.x += v.x; acc.y += v.y; acc.z += v.z; acc.w += v.w;
    }
    const float inv = 1.0f / (float)Tt;
    acc.x *= inv; acc.y *= inv; acc.z *= inv; acc.w *= inv;
    ((float4*)(ht_mean + (size_t)b * H2))[d4] = acc;
}

// ---------------------------------------------------------------- c2[b,a] = ht_mean[b].w1_w[a,1024:] + w1_b[a]
__global__ __launch_bounds__(256) void c2_kernel2(const float* __restrict__ ht_mean,
                                                  const float* __restrict__ w1_w,
                                                  const float* __restrict__ w1_b,
                                                  float* __restrict__ c2) {
    __shared__ float hm[H2];
    int b = blockIdx.x;
    for (int i = threadIdx.x; i < H2; i += 256) hm[i] = ht_mean[(size_t)b * H2 + i];
    __syncthreads();
    int a = blockIdx.y * 64 + ((int)threadIdx.x >> 2);
    int q = (int)threadIdx.x & 3;
    const float4* w   = (const float4*)(w1_w + (size_t)a * FF + H2 + q * 256);
    const float4* hm4 = (const float4*)(hm + q * 256);
    float acc = 0.f;
    #pragma unroll 8
    for (int k = 0; k < 64; ++k) {
        float4 wv = w[k]; float4 hv = hm4[k];
        acc += wv.x * hv.x + wv.y * hv.y + wv.z * hv.z + wv.w * hv.w;
    }
    acc += __shfl_xor(acc, 1);
    acc += __shfl_xor(acc, 2);
    if (q == 0) c2[(size_t)b * ATT + a] = acc + w1_b[a];
}

// ---------------------------------------------------------------- w1a_bf[a][k] = bf16(w1_w[a][k]), k<1024
__global__ void convw_kernel(const float* __restrict__ w1_w, unsigned short* __restrict__ out) {
    size_t e = ((size_t)blockIdx.x * 256 + threadIdx.x) * 8;
    int row = (int)(e >> 10);
    int c = (int)(e & 1023);
    const float* src = w1_w + (size_t)row * FF + c;
    float4 a = *(const float4*)(src);
    float4 b = *(const float4*)(src + 4);
    bf8 v = { (short)f2bf(a.x), (short)f2bf(a.y), (short)f2bf(a.z), (short)f2bf(a.w),
              (short)f2bf(b.x), (short)f2bf(b.y), (short)f2bf(b.z), (short)f2bf(b.w) };
    *(bf8*)(out + e) = v;
}

// ---------------------------------------------------------------- fused GEMM: M=32768, N=512(full), K=1024
// BM=64 x BN=512, BK=32, 8 waves (1m x 8n). Double-buffered LDS, one barrier per K-step,
// A prefetched to regs (fp32->bf16 in-reg), B via per-lane-source-swizzled global_load_lds.
// LDS slot swizzle: 16B slot s stored at s ^ ((row>>1)&3)  -> conflict-free ds_read_b128.
__global__ __launch_bounds__(512, 4) void gemm_fused2_kernel(
        const float* __restrict__ h, const unsigned short* __restrict__ wb,
        const float* __restrict__ c2, const float* __restrict__ u_w,
        float* __restrict__ beta) {
    __shared__ __align__(16) unsigned short As[2][BM * BK];   // 8 KB
    __shared__ __align__(16) unsigned short Bs[2][BN * BK];   // 64 KB
    __shared__ float red[8][64];                              // 2 KB

    const int tid = (int)threadIdx.x;
    const int m0 = blockIdx.x * BM;
    const int wid = tid >> 6, lane = tid & 63;
    const int col = lane & 15, rg = lane >> 4;
    const int rswz = rg ^ ((col >> 1) & 3);       // read-slot after swizzle

    f4 acc[4][4] = {};

    // A staging map: thread -> (row=tid>>3, 8B chunk tid&7). Swizzled LDS elem offset:
    const int arow = tid >> 3;
    const int asub = tid & 7;
    const int a_elem = arow * BK + ((((asub >> 1) ^ ((arow >> 1) & 3)) * 8) + (asub & 1) * 4);
    const float* Ag = h + (size_t)(m0 + arow) * H2 + asub * 4;

    // B staging: 4 gl_lds chunks; LDS dest linear, global source slot pre-swizzled.
    const int brow = tid >> 2;                         // 0..127 within chunk
    const int bslot_src = (tid & 3) ^ ((tid >> 3) & 3);
    const int ldsbase = wid * 512;                     // shorts; +c*4096; HW adds lane*16B

    // ---- prologue: stage tile 0
    #pragma unroll
    for (int c = 0; c < 4; ++c)
        gl_lds16(wb + (size_t)(c * 128 + brow) * H2 + bslot_src * 8,
                 &Bs[0][ldsbase + c * 4096]);
    {
        float4 a4 = *(const float4*)(Ag);
        bf4 ab = { (short)f2bf(a4.x), (short)f2bf(a4.y), (short)f2bf(a4.z), (short)f2bf(a4.w) };
        *(bf4*)&As[0][a_elem] = ab;
    }
    __syncthreads();

    int cur = 0;
    for (int t = 0; t < 32; ++t) {
        // ---- issue next-tile loads first (drain at end-of-iter barrier -> hidden)
        float4 a4n;
        if (t < 31) {
            a4n = *(const float4*)(Ag + (t + 1) * BK);
            #pragma unroll
            for (int c = 0; c < 4; ++c)
                gl_lds16(wb + (size_t)(c * 128 + brow) * H2 + (t + 1) * BK + bslot_src * 8,
                         &Bs[cur ^ 1][ldsbase + c * 4096]);
        }
        // ---- compute current tile
        bf8 av[4], bv[4];
        #pragma unroll
        for (int i = 0; i < 4; ++i) {
            av[i] = *(const bf8*)&As[cur][(i * 16 + col) * BK + rswz * 8];
            bv[i] = *(const bf8*)&Bs[cur][(wid * 64 + i * 16 + col) * BK + rswz * 8];
        }
        #pragma unroll
        for (int i = 0; i < 4; ++i)
            #pragma unroll
            for (int j = 0; j < 4; ++j)
                acc[i][j] = __builtin_amdgcn_mfma_f32_16x16x32_bf16(av[i], bv[j], acc[i][j], 0, 0, 0);
        // ---- convert+write next A tile (waits only the a4n load, vmcnt(4))
        if (t < 31) {
            bf4 ab = { (short)f2bf(a4n.x), (short)f2bf(a4n.y), (short)f2bf(a4n.z), (short)f2bf(a4n.w) };
            *(bf4*)&As[cur ^ 1][a_elem] = ab;
        }
        __syncthreads();   // drains gl_lds(t+1) + ds_writes; one barrier per K-step
        cur ^= 1;
    }

    // ---- epilogue: rp[i][r] = sum_n tanh(acc + c2[n]) * u[n] over wave's 64-col strip
    const int b_idx = blockIdx.x >> 3;     // m0 / Ss
    const float* c2b = c2 + (size_t)b_idx * ATT + wid * 64;
    const float* ub  = u_w + wid * 64;
    float rp[4][4] = {};
    #pragma unroll
    for (int j = 0; j < 4; ++j) {
        int n = j * 16 + col;
        float cv = c2b[n];
        float uv = ub[n];
        #pragma unroll
        for (int i = 0; i < 4; ++i)
            #pragma unroll
            for (int r = 0; r < 4; ++r)
                rp[i][r] += tanh_fast(acc[i][j][r] + cv) * uv;
    }
    #pragma unroll
    for (int i = 0; i < 4; ++i)
        #pragma unroll
        for (int r = 0; r < 4; ++r) {
            float v = rp[i][r];
            v += __shfl_xor(v, 1);
            v += __shfl_xor(v, 2);
            v += __shfl_xor(v, 4);
            v += __shfl_xor(v, 8);
            if (col == 0) red[wid][i * 16 + rg * 4 + r] = v;
        }
    __syncthreads();
    if (tid < 64) {
        float s = 0.f;
        #pragma unroll
        for (int w = 0; w < 8; ++w) s += red[w][tid];
        beta[(size_t)m0 + tid] = s;
    }
}

// ---------------------------------------------------------------- masked softmax over S
__global__ void softmax_kernel(const float* __restrict__ beta, const int* __restrict__ h_mask,
                               float* __restrict__ alpha) {
    __shared__ float red[16];
    int b = blockIdx.x;
    int s = (int)threadIdx.x;
    float v = (h_mask[(size_t)b * Ss + s] != 0) ? beta[(size_t)b * Ss + s] : -1e20f;
    float m = v;
    #pragma unroll
    for (int off = 32; off >= 1; off >>= 1) m = fmaxf(m, __shfl_xor(m, off, 64));
    int wave = s >> 6;
    if ((s & 63) == 0) red[wave] = m;
    __syncthreads();
    float mx = red[0];
    #pragma unroll
    for (int w = 1; w < 8; ++w) mx = fmaxf(mx, red[w]);
    float e = expf(v - mx);
    float sum = e;
    #pragma unroll
    for (int off = 32; off >= 1; off >>= 1) sum += __shfl_xor(sum, off, 64);
    __syncthreads();
    if ((s & 63) == 0) red[8 + wave] = sum;
    __syncthreads();
    float tot = 0.f;
    #pragma unroll
    for (int w = 0; w < 8; ++w) tot += red[8 + w];
    alpha[(size_t)b * Ss + s] = e / tot;
}

// ---------------------------------------------------------------- s[b,d] = sum_s alpha[b,s] h[b,s,d]
__global__ void wsum_kernel(const float* __restrict__ h, const float* __restrict__ alpha,
                            float* __restrict__ out) {
    int b = blockIdx.x;
    int d = blockIdx.y * 256 + (int)threadIdx.x;
    int s0 = blockIdx.z * 128;
    const float* hp = h + (size_t)b * Ss * H2 + (size_t)s0 * H2 + d;
    const float* ap = alpha + (size_t)b * Ss + s0;
    float acc = 0.f;
    #pragma unroll 4
    for (int s = 0; s < 128; ++s) acc = fmaf(ap[s], hp[(size_t)s * H2], acc);
    atomicAdd(&out[(size_t)b * H2 + d], acc);
}

// ---------------------------------------------------------------- launch
extern "C" void kernel_launch(void* const* d_in, const int* in_sizes, int n_in,
                              void* d_out, int out_size, void* d_ws, size_t ws_size,
                              hipStream_t stream) {
    const float* h      = (const float*)d_in[0];
    const int*   h_mask = (const int*)d_in[1];
    const float* ht     = (const float*)d_in[2];
    const float* w1_w   = (const float*)d_in[3];
    const float* w1_b   = (const float*)d_in[4];
    const float* u_w    = (const float*)d_in[5];
    float* out = (float*)d_out;

    float* ws      = (float*)d_ws;
    float* ht_mean = ws;                 // 65536 floats
    float* c2      = ws + 65536;         // 32768
    float* beta    = ws + 98304;         // 32768
    float* alpha   = ws + 131072;        // 32768
    unsigned short* w1a_bf = (unsigned short*)(ws + 164864);   // 1 MB (total ~1.7 MB)

    hipLaunchKernelGGL(init_kernel, dim3(Bb * H2 / 256), dim3(256), 0, stream, out);
    hipLaunchKernelGGL(mean_kernel, dim3(Bb), dim3(256), 0, stream, ht, ht_mean);
    hipLaunchKernelGGL(c2_kernel2, dim3(Bb, 8), dim3(256), 0, stream, ht_mean, w1_w, w1_b, c2);
    hipLaunchKernelGGL(convw_kernel, dim3(256), dim3(256), 0, stream, w1_w, w1a_bf);
    hipLaunchKernelGGL(gemm_fused2_kernel, dim3(MM / BM), dim3(512), 0, stream,
                       h, w1a_bf, c2, u_w, beta);
    hipLaunchKernelGGL(softmax_kernel, dim3(Bb), dim3(512), 0, stream, beta, h_mask, alpha);
    hipLaunchKernelGGL(wsum_kernel, dim3(Bb, H2 / 256, 4), dim3(256), 0, stream, h, alpha, out);
}